// Round 2
// baseline (181.955 us; speedup 1.0000x reference)
//
#include <hip/hip_runtime.h>
#include <hip/hip_bf16.h>

// GAT on MI355X. N=4096, DIN=512, H=128, K=4 heads, DOUT=16, p(adj)=0.01.
// All inputs/outputs float32 (per reference dtypes); GEMM1 uses bf16 MFMA
// (inputs rounded RTN to bf16; 2% test threshold >> 0.3% rounding error).

typedef __attribute__((ext_vector_type(4))) float floatx4;
typedef __attribute__((ext_vector_type(8))) short short8;
typedef unsigned short u16b;

#define GN 4096

__device__ __forceinline__ u16b f2bf(float f) {
  union { float f; unsigned int i; } v; v.f = f;
  unsigned int r = v.i + 0x7FFF + ((v.i >> 16) & 1);   // RTN-even
  return (u16b)(r >> 16);
}

// ---- K0: pack W1 (K,DIN,H) f32 -> Wt (KH x DIN) bf16, Wt[c][i] = W1[c>>7][i][c&127]
__global__ void k_pack(const float* __restrict__ W1, u16b* __restrict__ Wt) {
  int idx = blockIdx.x * 256 + threadIdx.x;          // 512*512 total
  int c = idx >> 9, i = idx & 511;
  Wt[(size_t)c * 512 + i] = f2bf(W1[((size_t)(c >> 7) * 512 + i) * 128 + (c & 127)]);
}

// ---- K1: Wh1f (4096 x 512 f32) = X(f32->bf16 inline) @ Wcat(bf16). 16x16 tile/wave, K=512.
__global__ __launch_bounds__(256) void k_gemm1(const float* __restrict__ X,
                                               const u16b* __restrict__ Wt,
                                               float* __restrict__ Wh1f) {
  int wave = threadIdx.x >> 6, lane = threadIdx.x & 63;
  int lh = lane >> 4, lm = lane & 15;
  int rbase = blockIdx.x * 16;                 // gridDim.x = 256
  int cbase = blockIdx.y * 64 + wave * 16;     // gridDim.y = 8
  floatx4 acc = {0.f, 0.f, 0.f, 0.f};
  const float* xp = X + (size_t)(rbase + lm) * 512 + lh * 8;
  const u16b* wp = Wt + (size_t)(cbase + lm) * 512 + lh * 8;
#pragma unroll
  for (int kk = 0; kk < 512; kk += 32) {
    floatx4 x0 = *(const floatx4*)(xp + kk);
    floatx4 x1 = *(const floatx4*)(xp + kk + 4);
    short8 a;
    a[0] = (short)f2bf(x0[0]); a[1] = (short)f2bf(x0[1]);
    a[2] = (short)f2bf(x0[2]); a[3] = (short)f2bf(x0[3]);
    a[4] = (short)f2bf(x1[0]); a[5] = (short)f2bf(x1[1]);
    a[6] = (short)f2bf(x1[2]); a[7] = (short)f2bf(x1[3]);
    short8 b = *(const short8*)(wp + kk);
    acc = __builtin_amdgcn_mfma_f32_16x16x32_bf16(a, b, acc, 0, 0, 0);
  }
  // C/D layout: col = lane&15, row = (lane>>4)*4 + j   [measured m89]
#pragma unroll
  for (int j = 0; j < 4; ++j)
    Wh1f[(size_t)(rbase + lh * 4 + j) * 512 + cbase + lm] = acc[j];
}

// ---- K1b: src1t[n][k], dst1t[n][k] = Wh1 head-dot a_src1/a_dst1. One wave per row.
__global__ __launch_bounds__(256) void k_srcdst1(const float* __restrict__ Wh1f,
    const float* __restrict__ as1, const float* __restrict__ ad1,
    float* __restrict__ src1t, float* __restrict__ dst1t) {
  int wave = threadIdx.x >> 6, lane = threadIdx.x & 63;
  int n = blockIdx.x * 4 + wave;               // gridDim.x = 1024
  int k = lane >> 4;
  const float* row = Wh1f + (size_t)n * 512 + lane * 8;
  int aoff = (k << 7) + (lane & 15) * 8;
  float s = 0.f, d = 0.f;
#pragma unroll
  for (int j = 0; j < 8; ++j) {
    float wv = row[j];
    s = fmaf(wv, as1[aoff + j], s);
    d = fmaf(wv, ad1[aoff + j], d);
  }
#pragma unroll
  for (int off = 8; off >= 1; off >>= 1) {
    s += __shfl_xor(s, off, 16);
    d += __shfl_xor(d, off, 16);
  }
  if ((lane & 15) == 0) { src1t[n * 4 + k] = s; dst1t[n * 4 + k] = d; }
}

// ---- shared: build compacted neighbor list for row n (mask = adj!=0 || m==n), deterministic order.
__device__ __forceinline__ int build_list(const float* __restrict__ arow, int n, int t,
                                          int* list, int* wcnt, int* s_cnt) {
  int lane = t & 63, w = t >> 6;
  if (t == 0) *s_cnt = 0;
  __syncthreads();
  for (int ch = 0; ch < 16; ++ch) {
    int m = ch * 256 + t;
    bool flag = (arow[m] != 0.f) | (m == n);
    unsigned long long b = __ballot(flag);
    if (lane == 0) wcnt[w] = __popcll(b);
    __syncthreads();
    int base = *s_cnt;
    int pre = 0;
    for (int w2 = 0; w2 < w; ++w2) pre += wcnt[w2];
    if (flag) list[base + pre + __popcll(b & ((1ull << lane) - 1ull))] = m;
    __syncthreads();
    if (t == 0) *s_cnt = base + wcnt[0] + wcnt[1] + wcnt[2] + wcnt[3];
    __syncthreads();
  }
  return *s_cnt;
}

// ---- K2: layer-1 attention + ELU. One block (256t) per row n. h1f[n][c], c = k*128+h.
__global__ __launch_bounds__(256) void k_attn1(const float* __restrict__ adj,
    const float* __restrict__ Wh1f, const float* __restrict__ src1t,
    const float* __restrict__ dst1t, float* __restrict__ h1f) {
  int n = blockIdx.x, t = threadIdx.x;
  __shared__ int list[512];
  __shared__ int wcnt[4];
  __shared__ int s_cnt;
  __shared__ float rmx[4][256];
  __shared__ float rsm[4][256];
  int cnt = build_list(adj + (size_t)n * 4096, n, t, list, wcnt, &s_cnt);

  float sn[4];
#pragma unroll
  for (int k = 0; k < 4; ++k) sn[k] = src1t[n * 4 + k];
  float mx[4], sm[4];
#pragma unroll
  for (int k = 0; k < 4; ++k) { mx[k] = -1e30f; sm[k] = 0.f; }
  for (int li = t; li < cnt; li += 256) {
    int m = list[li];
#pragma unroll
    for (int k = 0; k < 4; ++k) {
      float e = sn[k] + dst1t[m * 4 + k];
      e = e > 0.f ? e : 0.2f * e;
      if (e > mx[k]) { sm[k] = sm[k] * __expf(mx[k] - e) + 1.f; mx[k] = e; }
      else sm[k] += __expf(e - mx[k]);
    }
  }
#pragma unroll
  for (int k = 0; k < 4; ++k) { rmx[k][t] = mx[k]; rsm[k][t] = sm[k]; }
  __syncthreads();
  for (int s = 128; s > 0; s >>= 1) {
    if (t < s) {
#pragma unroll
      for (int k = 0; k < 4; ++k) {
        float Ma = rmx[k][t], Mb = rmx[k][t + s];
        float Sa = rsm[k][t], Sb = rsm[k][t + s];
        float M = fmaxf(Ma, Mb);
        rmx[k][t] = M;
        rsm[k][t] = Sa * __expf(Ma - M) + Sb * __expf(Mb - M);
      }
    }
    __syncthreads();
  }
  int k0 = t >> 7, k1 = k0 + 2;                 // thread t owns cols t (head k0) and 256+t (head k1)
  float M0 = rmx[k0][0], M1 = rmx[k1][0];
  float R0 = 1.f / rsm[k0][0], R1 = 1.f / rsm[k1][0];
  float sA = sn[k0], sB = sn[k1];
  float acc0 = 0.f, acc1 = 0.f;
  for (int li = 0; li < cnt; ++li) {
    int m = list[li];
    float e0 = sA + dst1t[m * 4 + k0]; e0 = e0 > 0.f ? e0 : 0.2f * e0;
    float e1 = sB + dst1t[m * 4 + k1]; e1 = e1 > 0.f ? e1 : 0.2f * e1;
    float w0 = __expf(e0 - M0) * R0;
    float w1 = __expf(e1 - M1) * R1;
    const float* wh = Wh1f + (size_t)m * 512;
    acc0 = fmaf(w0, wh[t], acc0);
    acc1 = fmaf(w1, wh[256 + t], acc1);
  }
  float o0 = acc0 > 0.f ? acc0 : __expf(acc0) - 1.f;   // ELU
  float o1 = acc1 > 0.f ? acc1 : __expf(acc1) - 1.f;
  h1f[(size_t)n * 512 + t] = o0;
  h1f[(size_t)n * 512 + 256 + t] = o1;
}

// ---- K3: Wh2 (4096x16 f32) = h1f @ W2(f32), fused src2/dst2. One block per row.
__global__ __launch_bounds__(256) void k_gemm2(const float* __restrict__ h1f,
    const float* __restrict__ W2, const float* __restrict__ as2, const float* __restrict__ ad2,
    float* __restrict__ Wh2, float* __restrict__ src2, float* __restrict__ dst2) {
  int n = blockIdx.x, t = threadIdx.x;
  int o = t & 15, ib = t >> 4;
  const float* hrow = h1f + (size_t)n * 512;
  float acc = 0.f;
  for (int i = ib; i < 512; i += 16)
    acc = fmaf(hrow[i], W2[i * 16 + o], acc);
  __shared__ float red[256];
  red[t] = acc;
  __syncthreads();
  for (int s = 128; s >= 16; s >>= 1) {
    if (t < s) red[t] += red[t + s];
    __syncthreads();
  }
  if (t < 16) {
    float v = red[t];
    Wh2[n * 16 + t] = v;
    float ps = v * as2[t];
    float pd = v * ad2[t];
#pragma unroll
    for (int off = 8; off >= 1; off >>= 1) {
      ps += __shfl_xor(ps, off, 16);
      pd += __shfl_xor(pd, off, 16);
    }
    if (t == 0) { src2[n] = ps; dst2[n] = pd; }
  }
}

// ---- K4: layer-2 attention + log_softmax -> f32 out. One block per row.
__global__ __launch_bounds__(256) void k_attn2(const float* __restrict__ adj,
    const float* __restrict__ Wh2, const float* __restrict__ src2,
    const float* __restrict__ dst2, float* __restrict__ out) {
  int n = blockIdx.x, t = threadIdx.x;
  __shared__ int list[512];
  __shared__ int wcnt[4];
  __shared__ int s_cnt;
  __shared__ float rmx[256];
  __shared__ float rsm[256];
  __shared__ float red16[256 * 16];
  int cnt = build_list(adj + (size_t)n * 4096, n, t, list, wcnt, &s_cnt);

  float snv = src2[n];
  float mx = -1e30f, sm = 0.f;
  for (int li = t; li < cnt; li += 256) {
    int m = list[li];
    float e = snv + dst2[m]; e = e > 0.f ? e : 0.2f * e;
    if (e > mx) { sm = sm * __expf(mx - e) + 1.f; mx = e; }
    else sm += __expf(e - mx);
  }
  rmx[t] = mx; rsm[t] = sm;
  __syncthreads();
  for (int s = 128; s > 0; s >>= 1) {
    if (t < s) {
      float Ma = rmx[t], Mb = rmx[t + s], Sa = rsm[t], Sb = rsm[t + s];
      float M = fmaxf(Ma, Mb);
      rmx[t] = M; rsm[t] = Sa * __expf(Ma - M) + Sb * __expf(Mb - M);
    }
    __syncthreads();
  }
  float M = rmx[0], R = 1.f / rsm[0];
  float acc[16];
#pragma unroll
  for (int o = 0; o < 16; ++o) acc[o] = 0.f;
  for (int li = t; li < cnt; li += 256) {
    int m = list[li];
    float e = snv + dst2[m]; e = e > 0.f ? e : 0.2f * e;
    float wgt = __expf(e - M) * R;
    const float* wm = Wh2 + m * 16;
#pragma unroll
    for (int o = 0; o < 16; ++o) acc[o] = fmaf(wgt, wm[o], acc[o]);
  }
#pragma unroll
  for (int o = 0; o < 16; ++o) red16[t * 16 + o] = acc[o];
  __syncthreads();
  for (int s = 128; s > 0; s >>= 1) {
    if (t < s) {
#pragma unroll
      for (int o = 0; o < 16; ++o) red16[t * 16 + o] += red16[(t + s) * 16 + o];
    }
    __syncthreads();
  }
  if (t < 16) {
    float v = red16[t];
    float vm = v;
#pragma unroll
    for (int off = 8; off >= 1; off >>= 1) vm = fmaxf(vm, __shfl_xor(vm, off, 16));
    float ex = __expf(v - vm);
#pragma unroll
    for (int off = 8; off >= 1; off >>= 1) ex += __shfl_xor(ex, off, 16);
    out[n * 16 + t] = v - vm - __logf(ex);
  }
}

extern "C" void kernel_launch(void* const* d_in, const int* in_sizes, int n_in,
                              void* d_out, int out_size, void* d_ws, size_t ws_size,
                              hipStream_t stream) {
  const float* X   = (const float*)d_in[0];   // (4096,512)
  const float* adj = (const float*)d_in[1];   // (4096,4096)
  const float* W1  = (const float*)d_in[2];   // (4,512,128)
  const float* as1 = (const float*)d_in[3];   // (4,128)
  const float* ad1 = (const float*)d_in[4];   // (4,128)
  const float* W2  = (const float*)d_in[5];   // (512,16)
  const float* as2 = (const float*)d_in[6];   // (16,)
  const float* ad2 = (const float*)d_in[7];   // (16,)
  float* out = (float*)d_out;

  // workspace layout (~17 MB)
  char* ws = (char*)d_ws;
  u16b*  Wt    = (u16b*)ws;                          // 512 KB  bf16 [c][i]
  float* src1t = (float*)(ws + (512 << 10));         // 64 KB   [n][k]
  float* dst1t = (float*)(ws + (576 << 10));         // 64 KB   [n][k]
  float* src2  = (float*)(ws + (640 << 10));         // 16 KB
  float* dst2  = (float*)(ws + (656 << 10));         // 16 KB
  float* Wh2   = (float*)(ws + (672 << 10));         // 256 KB
  float* Wh1f  = (float*)(ws + (1ull << 20));        // 8 MB    [n][k*128+h]
  float* h1f   = (float*)(ws + (9ull << 20));        // 8 MB

  k_pack<<<dim3(1024), dim3(256), 0, stream>>>(W1, Wt);
  k_gemm1<<<dim3(256, 8), dim3(256), 0, stream>>>(X, Wt, Wh1f);
  k_srcdst1<<<dim3(1024), dim3(256), 0, stream>>>(Wh1f, as1, ad1, src1t, dst1t);
  k_attn1<<<dim3(GN), dim3(256), 0, stream>>>(adj, Wh1f, src1t, dst1t, h1f);
  k_gemm2<<<dim3(GN), dim3(256), 0, stream>>>(h1f, W2, as2, ad2, Wh2, src2, dst2);
  k_attn2<<<dim3(GN), dim3(256), 0, stream>>>(adj, Wh2, src2, dst2, out);
}

// Round 3
// 119.444 us; speedup vs baseline: 1.5234x; 1.5234x over previous
//
#include <hip/hip_runtime.h>
#include <hip/hip_bf16.h>

// GAT on MI355X. N=4096, DIN=512, H=128, K=4 heads, DOUT=16, p(adj)=0.01.
// f32 in/out. bf16 MFMA GEMM1; Wh1/h1 stored bf16; CSR built once from adj.

typedef __attribute__((ext_vector_type(4))) float floatx4;
typedef __attribute__((ext_vector_type(8))) short short8;
typedef __attribute__((ext_vector_type(4))) unsigned short ushortx4;
typedef unsigned short u16b;

#define GN 4096

__device__ __forceinline__ u16b f2bf(float f) {
  union { float f; unsigned int i; } v; v.f = f;
  unsigned int r = v.i + 0x7FFF + ((v.i >> 16) & 1);   // RTN-even
  return (u16b)(r >> 16);
}
__device__ __forceinline__ float bflo(unsigned u) {
  union { unsigned i; float f; } v; v.i = u << 16; return v.f;
}
__device__ __forceinline__ float bfhi(unsigned u) {
  union { unsigned i; float f; } v; v.i = u & 0xffff0000u; return v.f;
}

// ---- K0: pack W1 (K,DIN,H) f32 -> Wt (KH x DIN) bf16, Wt[c][i] = W1[c>>7][i][c&127]
__global__ void k_pack(const float* __restrict__ W1, u16b* __restrict__ Wt) {
  int idx = blockIdx.x * 256 + threadIdx.x;          // 512*512
  int c = idx >> 9, i = idx & 511;
  Wt[(size_t)c * 512 + i] = f2bf(W1[((size_t)(c >> 7) * 512 + i) * 128 + (c & 127)]);
}

// ---- K0b: X f32 -> Xbf bf16 (2M elems, 4/thread)
__global__ void k_convX(const float* __restrict__ X, u16b* __restrict__ Xbf) {
  int idx = blockIdx.x * 256 + threadIdx.x;
  floatx4 v = *(const floatx4*)(X + (size_t)idx * 4);
  ushortx4 o;
  o[0] = f2bf(v[0]); o[1] = f2bf(v[1]); o[2] = f2bf(v[2]); o[3] = f2bf(v[3]);
  *(ushortx4*)(Xbf + (size_t)idx * 4) = o;
}

// ---- K1: CSR build. One block per row; single __syncthreads (ballots in regs).
__global__ __launch_bounds__(256) void k_build(const float* __restrict__ adj,
    u16b* __restrict__ csr, int* __restrict__ counts) {
  int n = blockIdx.x, t = threadIdx.x, lane = t & 63, w = t >> 6;
  __shared__ int cnt_cw[64];                         // [ch][wave]
  const float* arow = adj + (size_t)n * 4096;
  unsigned fl = 0;
  unsigned long long bal[16];
#pragma unroll
  for (int ch = 0; ch < 16; ++ch) {
    int m = ch * 256 + t;
    bool f = (arow[m] != 0.f) | (m == n);
    fl |= (unsigned)f << ch;
    unsigned long long b = __ballot(f);
    bal[ch] = b;
    if (lane == 0) cnt_cw[ch * 4 + w] = __popcll(b);
  }
  __syncthreads();
  int off[16];
  int run = 0;
#pragma unroll
  for (int ch = 0; ch < 16; ++ch) {
    int pre = run;
    for (int w2 = 0; w2 < w; ++w2) pre += cnt_cw[ch * 4 + w2];
    off[ch] = pre;
    run += cnt_cw[ch * 4] + cnt_cw[ch * 4 + 1] + cnt_cw[ch * 4 + 2] + cnt_cw[ch * 4 + 3];
  }
  if (t == 0) counts[n] = run;
  u16b* row = csr + (size_t)n * 512;
#pragma unroll
  for (int ch = 0; ch < 16; ++ch)
    if ((fl >> ch) & 1)
      row[off[ch] + __popcll(bal[ch] & ((1ull << lane) - 1ull))] = (u16b)(ch * 256 + t);
}

// ---- K2: Wh1bf (4096 x 512 bf16) = Xbf @ Wcat. 16x16 MFMA tile/wave, K=512.
__global__ __launch_bounds__(256) void k_gemm1(const u16b* __restrict__ Xbf,
                                               const u16b* __restrict__ Wt,
                                               u16b* __restrict__ Wh1bf) {
  int wave = threadIdx.x >> 6, lane = threadIdx.x & 63;
  int lh = lane >> 4, lm = lane & 15;
  int rbase = blockIdx.x * 16;                 // gridDim.x = 256
  int cbase = blockIdx.y * 64 + wave * 16;     // gridDim.y = 8
  floatx4 acc = {0.f, 0.f, 0.f, 0.f};
  const u16b* xp = Xbf + (size_t)(rbase + lm) * 512 + lh * 8;
  const u16b* wp = Wt + (size_t)(cbase + lm) * 512 + lh * 8;
#pragma unroll
  for (int kk = 0; kk < 512; kk += 32) {
    short8 a = *(const short8*)(xp + kk);
    short8 b = *(const short8*)(wp + kk);
    acc = __builtin_amdgcn_mfma_f32_16x16x32_bf16(a, b, acc, 0, 0, 0);
  }
  // C/D layout: col = lane&15, row = (lane>>4)*4 + j   [m89]
#pragma unroll
  for (int j = 0; j < 4; ++j)
    Wh1bf[(size_t)(rbase + lh * 4 + j) * 512 + cbase + lm] = f2bf(acc[j]);
}

// ---- K3: src1t[n][k], dst1t[n][k] from Wh1bf. One wave per row.
__global__ __launch_bounds__(256) void k_srcdst1(const u16b* __restrict__ Wh1bf,
    const float* __restrict__ as1, const float* __restrict__ ad1,
    float* __restrict__ src1t, float* __restrict__ dst1t) {
  int wave = threadIdx.x >> 6, lane = threadIdx.x & 63;
  int n = blockIdx.x * 4 + wave;               // gridDim.x = 1024
  int k = lane >> 4;
  short8 v = *(const short8*)(Wh1bf + (size_t)n * 512 + lane * 8);
  int aoff = (k << 7) + (lane & 15) * 8;
  float s = 0.f, d = 0.f;
#pragma unroll
  for (int j = 0; j < 8; ++j) {
    union { unsigned i; float f; } u; u.i = ((unsigned)(u16b)v[j]) << 16;
    s = fmaf(u.f, as1[aoff + j], s);
    d = fmaf(u.f, ad1[aoff + j], d);
  }
#pragma unroll
  for (int off = 8; off >= 1; off >>= 1) {
    s += __shfl_xor(s, off, 16);
    d += __shfl_xor(d, off, 16);
  }
  if ((lane & 15) == 0) { src1t[n * 4 + k] = s; dst1t[n * 4 + k] = d; }
}

// ---- K4: layer-1 attention + ELU. Block per row. Weights precomputed in LDS.
__global__ __launch_bounds__(256) void k_attn1(const u16b* __restrict__ csr,
    const int* __restrict__ counts, const u16b* __restrict__ Wh1bf,
    const float* __restrict__ src1t, const float* __restrict__ dst1t,
    unsigned* __restrict__ h1bf) {
  int n = blockIdx.x, t = threadIdx.x, lane = t & 63, w = t >> 6;
  __shared__ u16b lst[512];
  __shared__ float ew[4][516];                 // padded: stride 516 breaks 4-way bank conflict
  int cnt = counts[n];
  const u16b* row = csr + (size_t)n * 512;
  for (int i = t; i < cnt; i += 256) lst[i] = row[i];
  float sn[4];
#pragma unroll
  for (int k = 0; k < 4; ++k) sn[k] = src1t[n * 4 + k];
  __syncthreads();
  // fill leaky-relu logits: thread j -> (li=j>>2, k=j&3)
  for (int j = t; j < cnt * 4; j += 256) {
    int li = j >> 2, k = j & 3;
    int m = lst[li];
    float e = sn[k] + dst1t[m * 4 + k];
    ew[k][li] = e > 0.f ? e : 0.2f * e;
  }
  __syncthreads();
  // per-wave softmax over head w, normalize in place
  {
    float mx = -1e30f, sm = 0.f;
    for (int li = lane; li < cnt; li += 64) {
      float e = ew[w][li];
      if (e > mx) { sm = sm * __expf(mx - e) + 1.f; mx = e; }
      else sm += __expf(e - mx);
    }
#pragma unroll
    for (int off = 32; off >= 1; off >>= 1) {
      float mo = __shfl_xor(mx, off);
      float so = __shfl_xor(sm, off);
      float M = fmaxf(mx, mo);
      sm = sm * __expf(mx - M) + so * __expf(mo - M);
      mx = M;
    }
    float R = 1.f / sm;
    for (int li = lane; li < cnt; li += 64)
      ew[w][li] = __expf(ew[w][li] - mx) * R;
  }
  __syncthreads();
  // weighted gather: thread t owns cols 2t,2t+1 (head == w); bf16 pair loads
  float a0 = 0.f, a1 = 0.f;
  const float* ewk = ew[w];
#pragma unroll 4
  for (int li = 0; li < cnt; ++li) {
    int m = lst[li];
    float wv = ewk[li];
    unsigned u = *(const unsigned*)(Wh1bf + (size_t)m * 512 + 2 * t);
    a0 = fmaf(wv, bflo(u), a0);
    a1 = fmaf(wv, bfhi(u), a1);
  }
  a0 = a0 > 0.f ? a0 : __expf(a0) - 1.f;       // ELU
  a1 = a1 > 0.f ? a1 : __expf(a1) - 1.f;
  h1bf[(size_t)n * 256 + t] = (unsigned)f2bf(a0) | ((unsigned)f2bf(a1) << 16);
}

// ---- K5: Wh2 (4096x16 f32) = h1(bf16) @ W2(f32), fused src2/dst2. Block per row.
__global__ __launch_bounds__(256) void k_gemm2(const u16b* __restrict__ h1u,
    const float* __restrict__ W2, const float* __restrict__ as2, const float* __restrict__ ad2,
    float* __restrict__ Wh2, float* __restrict__ src2, float* __restrict__ dst2) {
  int n = blockIdx.x, t = threadIdx.x;
  int o = t & 15, ib = t >> 4;
  const u16b* hrow = h1u + (size_t)n * 512;
  float acc = 0.f;
  for (int i = ib; i < 512; i += 16) {
    union { unsigned ui; float f; } u; u.ui = ((unsigned)hrow[i]) << 16;
    acc = fmaf(u.f, W2[i * 16 + o], acc);
  }
  __shared__ float red[256];
  red[t] = acc;
  __syncthreads();
  for (int s = 128; s >= 16; s >>= 1) {
    if (t < s) red[t] += red[t + s];
    __syncthreads();
  }
  if (t < 16) {
    float v = red[t];
    Wh2[n * 16 + t] = v;
    float ps = v * as2[t];
    float pd = v * ad2[t];
#pragma unroll
    for (int off = 8; off >= 1; off >>= 1) {
      ps += __shfl_xor(ps, off, 16);
      pd += __shfl_xor(pd, off, 16);
    }
    if (t == 0) { src2[n] = ps; dst2[n] = pd; }
  }
}

// ---- K6: layer-2 attention + log_softmax. One wave per row (4 rows/block).
__global__ __launch_bounds__(256) void k_attn2(const u16b* __restrict__ csr,
    const int* __restrict__ counts, const float* __restrict__ Wh2,
    const float* __restrict__ src2, const float* __restrict__ dst2,
    float* __restrict__ out) {
  int w = threadIdx.x >> 6, lane = threadIdx.x & 63;
  int n = blockIdx.x * 4 + w;
  int cnt = counts[n];
  const u16b* row = csr + (size_t)n * 512;
  float snv = src2[n];
  float mx = -1e30f, sm = 0.f;
  for (int li = lane; li < cnt; li += 64) {
    int m = row[li];
    float e = snv + dst2[m]; e = e > 0.f ? e : 0.2f * e;
    if (e > mx) { sm = sm * __expf(mx - e) + 1.f; mx = e; }
    else sm += __expf(e - mx);
  }
#pragma unroll
  for (int off = 32; off >= 1; off >>= 1) {
    float mo = __shfl_xor(mx, off);
    float so = __shfl_xor(sm, off);
    float M = fmaxf(mx, mo);
    sm = sm * __expf(mx - M) + so * __expf(mo - M);
    mx = M;
  }
  float R = 1.f / sm;
  int o = lane & 15, g = lane >> 4;
  float acc = 0.f;
  for (int li = g; li < cnt; li += 4) {
    int m = row[li];
    float e = snv + dst2[m]; e = e > 0.f ? e : 0.2f * e;
    float wgt = __expf(e - mx) * R;
    acc = fmaf(wgt, Wh2[m * 16 + o], acc);
  }
  acc += __shfl_xor(acc, 16);
  acc += __shfl_xor(acc, 32);
  float vm = acc;
#pragma unroll
  for (int off = 8; off >= 1; off >>= 1) vm = fmaxf(vm, __shfl_xor(vm, off, 16));
  float ex = __expf(acc - vm);
#pragma unroll
  for (int off = 8; off >= 1; off >>= 1) ex += __shfl_xor(ex, off, 16);
  if (lane < 16) out[(size_t)n * 16 + lane] = acc - vm - __logf(ex);
}

extern "C" void kernel_launch(void* const* d_in, const int* in_sizes, int n_in,
                              void* d_out, int out_size, void* d_ws, size_t ws_size,
                              hipStream_t stream) {
  const float* X   = (const float*)d_in[0];
  const float* adj = (const float*)d_in[1];
  const float* W1  = (const float*)d_in[2];
  const float* as1 = (const float*)d_in[3];
  const float* ad1 = (const float*)d_in[4];
  const float* W2  = (const float*)d_in[5];
  const float* as2 = (const float*)d_in[6];
  const float* ad2 = (const float*)d_in[7];
  float* out = (float*)d_out;

  // workspace layout (17 MB total)
  char* ws = (char*)d_ws;
  u16b*  Wt    = (u16b*)ws;                          // 512 KB
  int*   counts= (int*)(ws + (512 << 10));           // 16 KB
  float* src1t = (float*)(ws + (528 << 10));         // 64 KB
  float* dst1t = (float*)(ws + (592 << 10));         // 64 KB
  float* src2  = (float*)(ws + (656 << 10));         // 16 KB
  float* dst2  = (float*)(ws + (672 << 10));         // 16 KB
  float* Wh2   = (float*)(ws + (688 << 10));         // 256 KB
  u16b*  Xbf   = (u16b*)(ws + (1ull << 20));         // 4 MB
  u16b*  Wh1bf = (u16b*)(ws + (5ull << 20));         // 4 MB
  u16b*  csr   = (u16b*)(ws + (9ull << 20));         // 4 MB
  unsigned* h1bf = (unsigned*)(ws + (13ull << 20));  // 4 MB

  k_pack <<<dim3(1024), dim3(256), 0, stream>>>(W1, Wt);
  k_convX<<<dim3(2048), dim3(256), 0, stream>>>(X, Xbf);
  k_build<<<dim3(GN),   dim3(256), 0, stream>>>(adj, csr, counts);
  k_gemm1<<<dim3(256,8),dim3(256), 0, stream>>>(Xbf, Wt, Wh1bf);
  k_srcdst1<<<dim3(1024),dim3(256),0, stream>>>(Wh1bf, as1, ad1, src1t, dst1t);
  k_attn1<<<dim3(GN),   dim3(256), 0, stream>>>(csr, counts, Wh1bf, src1t, dst1t, h1bf);
  k_gemm2<<<dim3(GN),   dim3(256), 0, stream>>>((const u16b*)h1bf, W2, as2, ad2, Wh2, src2, dst2);
  k_attn2<<<dim3(1024), dim3(256), 0, stream>>>(csr, counts, Wh2, src2, dst2, out);
}

// Round 4
// 102.778 us; speedup vs baseline: 1.7704x; 1.1622x over previous
//
#include <hip/hip_runtime.h>
#include <hip/hip_bf16.h>

// GAT on MI355X. N=4096, DIN=512, H=128, K=4 heads, DOUT=16, p(adj)=0.01.
// f32 in/out. bf16 MFMA GEMM1; Wh1/h1 stored bf16; CSR built once from adj
// (one wave per row, ballot compaction, deterministic j-major order).

typedef __attribute__((ext_vector_type(4))) float floatx4;
typedef __attribute__((ext_vector_type(8))) short short8;
typedef __attribute__((ext_vector_type(4))) unsigned short ushortx4;
typedef unsigned short u16b;

#define GN 4096

__device__ __forceinline__ u16b f2bf(float f) {
  union { float f; unsigned int i; } v; v.f = f;
  unsigned int r = v.i + 0x7FFF + ((v.i >> 16) & 1);   // RTN-even
  return (u16b)(r >> 16);
}
__device__ __forceinline__ float bflo(unsigned u) {
  union { unsigned i; float f; } v; v.i = u << 16; return v.f;
}
__device__ __forceinline__ float bfhi(unsigned u) {
  union { unsigned i; float f; } v; v.i = u & 0xffff0000u; return v.f;
}

// ---- K0: fused prep. Blocks [0,1024): W1 pack; [1024,3072): X f32->bf16.
// Wt[c][i] = W1[c>>7][i][c&127]
__global__ void k_prep(const float* __restrict__ W1, const float* __restrict__ X,
                       u16b* __restrict__ Wt, u16b* __restrict__ Xbf) {
  int b = blockIdx.x;
  if (b < 1024) {
    int idx = b * 256 + threadIdx.x;                 // 512*512
    int c = idx >> 9, i = idx & 511;
    Wt[(size_t)c * 512 + i] = f2bf(W1[((size_t)(c >> 7) * 512 + i) * 128 + (c & 127)]);
  } else {
    int idx = (b - 1024) * 256 + threadIdx.x;        // 2M elems / 4
    floatx4 v = *(const floatx4*)(X + (size_t)idx * 4);
    ushortx4 o;
    o[0] = f2bf(v[0]); o[1] = f2bf(v[1]); o[2] = f2bf(v[2]); o[3] = f2bf(v[3]);
    *(ushortx4*)(Xbf + (size_t)idx * 4) = o;
  }
}

// ---- K1: CSR build. One WAVE per row; no LDS, no syncthreads.
// Order within each 256-chunk is j-major (m%4 groups) — deterministic, unsorted (OK).
__global__ __launch_bounds__(256) void k_build(const float* __restrict__ adj,
    u16b* __restrict__ csr, int* __restrict__ counts) {
  int w = threadIdx.x >> 6, lane = threadIdx.x & 63;
  int n = blockIdx.x * 4 + w;
  const float* arow = adj + (size_t)n * 4096;
  u16b* row = csr + (size_t)n * 512;
  unsigned long long below = (1ull << lane) - 1ull;
  int run = 0;
#pragma unroll
  for (int ch = 0; ch < 16; ++ch) {
    int m0 = ch * 256 + lane * 4;
    floatx4 v = *(const floatx4*)(arow + m0);
    bool f0 = (v[0] != 0.f) | (m0     == n);
    bool f1 = (v[1] != 0.f) | (m0 + 1 == n);
    bool f2 = (v[2] != 0.f) | (m0 + 2 == n);
    bool f3 = (v[3] != 0.f) | (m0 + 3 == n);
    unsigned long long b0 = __ballot(f0), b1 = __ballot(f1);
    unsigned long long b2 = __ballot(f2), b3 = __ballot(f3);
    int c0 = __popcll(b0), c1 = __popcll(b1), c2 = __popcll(b2);
    if (f0) row[run +            __popcll(b0 & below)] = (u16b)m0;
    if (f1) row[run + c0 +       __popcll(b1 & below)] = (u16b)(m0 + 1);
    if (f2) row[run + c0+c1 +    __popcll(b2 & below)] = (u16b)(m0 + 2);
    if (f3) row[run + c0+c1+c2 + __popcll(b3 & below)] = (u16b)(m0 + 3);
    run += c0 + c1 + c2 + __popcll(b3);
  }
  if (lane == 0) counts[n] = run;
}

// ---- K2: Wh1bf (4096 x 512 bf16) = Xbf @ Wcat. 16x16 MFMA tile/wave, K=512.
__global__ __launch_bounds__(256) void k_gemm1(const u16b* __restrict__ Xbf,
                                               const u16b* __restrict__ Wt,
                                               u16b* __restrict__ Wh1bf) {
  int wave = threadIdx.x >> 6, lane = threadIdx.x & 63;
  int lh = lane >> 4, lm = lane & 15;
  int rbase = blockIdx.x * 16;                 // gridDim.x = 256
  int cbase = blockIdx.y * 64 + wave * 16;     // gridDim.y = 8
  floatx4 acc = {0.f, 0.f, 0.f, 0.f};
  const u16b* xp = Xbf + (size_t)(rbase + lm) * 512 + lh * 8;
  const u16b* wp = Wt + (size_t)(cbase + lm) * 512 + lh * 8;
#pragma unroll
  for (int kk = 0; kk < 512; kk += 32) {
    short8 a = *(const short8*)(xp + kk);
    short8 b = *(const short8*)(wp + kk);
    acc = __builtin_amdgcn_mfma_f32_16x16x32_bf16(a, b, acc, 0, 0, 0);
  }
  // C/D layout: col = lane&15, row = (lane>>4)*4 + j   [m89]
#pragma unroll
  for (int j = 0; j < 4; ++j)
    Wh1bf[(size_t)(rbase + lh * 4 + j) * 512 + cbase + lm] = f2bf(acc[j]);
}

// ---- K3: src1t[n][k], dst1t[n][k] from Wh1bf. One wave per row.
__global__ __launch_bounds__(256) void k_srcdst1(const u16b* __restrict__ Wh1bf,
    const float* __restrict__ as1, const float* __restrict__ ad1,
    float* __restrict__ src1t, float* __restrict__ dst1t) {
  int wave = threadIdx.x >> 6, lane = threadIdx.x & 63;
  int n = blockIdx.x * 4 + wave;               // gridDim.x = 1024
  int k = lane >> 4;
  short8 v = *(const short8*)(Wh1bf + (size_t)n * 512 + lane * 8);
  int aoff = (k << 7) + (lane & 15) * 8;
  float s = 0.f, d = 0.f;
#pragma unroll
  for (int j = 0; j < 8; ++j) {
    union { unsigned i; float f; } u; u.i = ((unsigned)(u16b)v[j]) << 16;
    s = fmaf(u.f, as1[aoff + j], s);
    d = fmaf(u.f, ad1[aoff + j], d);
  }
#pragma unroll
  for (int off = 8; off >= 1; off >>= 1) {
    s += __shfl_xor(s, off, 16);
    d += __shfl_xor(d, off, 16);
  }
  if ((lane & 15) == 0) { src1t[n * 4 + k] = s; dst1t[n * 4 + k] = d; }
}

// ---- K4: layer-1 attention + ELU. Block per row. Weights precomputed in LDS.
__global__ __launch_bounds__(256) void k_attn1(const u16b* __restrict__ csr,
    const int* __restrict__ counts, const u16b* __restrict__ Wh1bf,
    const float* __restrict__ src1t, const float* __restrict__ dst1t,
    unsigned* __restrict__ h1bf) {
  int n = blockIdx.x, t = threadIdx.x, lane = t & 63, w = t >> 6;
  __shared__ u16b lst[512];
  __shared__ float ew[4][516];                 // padded: stride 516 breaks 4-way bank conflict
  int cnt = counts[n];
  const u16b* row = csr + (size_t)n * 512;
  for (int i = t; i < cnt; i += 256) lst[i] = row[i];
  float sn[4];
#pragma unroll
  for (int k = 0; k < 4; ++k) sn[k] = src1t[n * 4 + k];
  __syncthreads();
  // fill leaky-relu logits: thread j -> (li=j>>2, k=j&3)
  for (int j = t; j < cnt * 4; j += 256) {
    int li = j >> 2, k = j & 3;
    int m = lst[li];
    float e = sn[k] + dst1t[m * 4 + k];
    ew[k][li] = e > 0.f ? e : 0.2f * e;
  }
  __syncthreads();
  // per-wave softmax over head w, normalize in place
  {
    float mx = -1e30f, sm = 0.f;
    for (int li = lane; li < cnt; li += 64) {
      float e = ew[w][li];
      if (e > mx) { sm = sm * __expf(mx - e) + 1.f; mx = e; }
      else sm += __expf(e - mx);
    }
#pragma unroll
    for (int off = 32; off >= 1; off >>= 1) {
      float mo = __shfl_xor(mx, off);
      float so = __shfl_xor(sm, off);
      float M = fmaxf(mx, mo);
      sm = sm * __expf(mx - M) + so * __expf(mo - M);
      mx = M;
    }
    float R = 1.f / sm;
    for (int li = lane; li < cnt; li += 64)
      ew[w][li] = __expf(ew[w][li] - mx) * R;
  }
  __syncthreads();
  // weighted gather: thread t owns cols 2t,2t+1 (head == w); bf16 pair loads
  float a0 = 0.f, a1 = 0.f;
  const float* ewk = ew[w];
#pragma unroll 4
  for (int li = 0; li < cnt; ++li) {
    int m = lst[li];
    float wv = ewk[li];
    unsigned u = *(const unsigned*)(Wh1bf + (size_t)m * 512 + 2 * t);
    a0 = fmaf(wv, bflo(u), a0);
    a1 = fmaf(wv, bfhi(u), a1);
  }
  a0 = a0 > 0.f ? a0 : __expf(a0) - 1.f;       // ELU
  a1 = a1 > 0.f ? a1 : __expf(a1) - 1.f;
  h1bf[(size_t)n * 256 + t] = (unsigned)f2bf(a0) | ((unsigned)f2bf(a1) << 16);
}

// ---- K5: Wh2 (4096x16 f32) = h1(bf16) @ W2(f32), fused src2/dst2. Block per row.
__global__ __launch_bounds__(256) void k_gemm2(const u16b* __restrict__ h1u,
    const float* __restrict__ W2, const float* __restrict__ as2, const float* __restrict__ ad2,
    float* __restrict__ Wh2, float* __restrict__ src2, float* __restrict__ dst2) {
  int n = blockIdx.x, t = threadIdx.x;
  int o = t & 15, ib = t >> 4;
  const u16b* hrow = h1u + (size_t)n * 512;
  float acc = 0.f;
  for (int i = ib; i < 512; i += 16) {
    union { unsigned ui; float f; } u; u.ui = ((unsigned)hrow[i]) << 16;
    acc = fmaf(u.f, W2[i * 16 + o], acc);
  }
  __shared__ float red[256];
  red[t] = acc;
  __syncthreads();
  for (int s = 128; s >= 16; s >>= 1) {
    if (t < s) red[t] += red[t + s];
    __syncthreads();
  }
  if (t < 16) {
    float v = red[t];
    Wh2[n * 16 + t] = v;
    float ps = v * as2[t];
    float pd = v * ad2[t];
#pragma unroll
    for (int off = 8; off >= 1; off >>= 1) {
      ps += __shfl_xor(ps, off, 16);
      pd += __shfl_xor(pd, off, 16);
    }
    if (t == 0) { src2[n] = ps; dst2[n] = pd; }
  }
}

// ---- K6: layer-2 attention + log_softmax. One wave per row (4 rows/block).
__global__ __launch_bounds__(256) void k_attn2(const u16b* __restrict__ csr,
    const int* __restrict__ counts, const float* __restrict__ Wh2,
    const float* __restrict__ src2, const float* __restrict__ dst2,
    float* __restrict__ out) {
  int w = threadIdx.x >> 6, lane = threadIdx.x & 63;
  int n = blockIdx.x * 4 + w;
  int cnt = counts[n];
  const u16b* row = csr + (size_t)n * 512;
  float snv = src2[n];
  float mx = -1e30f, sm = 0.f;
  for (int li = lane; li < cnt; li += 64) {
    int m = row[li];
    float e = snv + dst2[m]; e = e > 0.f ? e : 0.2f * e;
    if (e > mx) { sm = sm * __expf(mx - e) + 1.f; mx = e; }
    else sm += __expf(e - mx);
  }
#pragma unroll
  for (int off = 32; off >= 1; off >>= 1) {
    float mo = __shfl_xor(mx, off);
    float so = __shfl_xor(sm, off);
    float M = fmaxf(mx, mo);
    sm = sm * __expf(mx - M) + so * __expf(mo - M);
    mx = M;
  }
  float R = 1.f / sm;
  int o = lane & 15, g = lane >> 4;
  float acc = 0.f;
  for (int li = g; li < cnt; li += 4) {
    int m = row[li];
    float e = snv + dst2[m]; e = e > 0.f ? e : 0.2f * e;
    float wgt = __expf(e - mx) * R;
    acc = fmaf(wgt, Wh2[m * 16 + o], acc);
  }
  acc += __shfl_xor(acc, 16);
  acc += __shfl_xor(acc, 32);
  float vm = acc;
#pragma unroll
  for (int off = 8; off >= 1; off >>= 1) vm = fmaxf(vm, __shfl_xor(vm, off, 16));
  float ex = __expf(acc - vm);
#pragma unroll
  for (int off = 8; off >= 1; off >>= 1) ex += __shfl_xor(ex, off, 16);
  if (lane < 16) out[(size_t)n * 16 + lane] = acc - vm - __logf(ex);
}

extern "C" void kernel_launch(void* const* d_in, const int* in_sizes, int n_in,
                              void* d_out, int out_size, void* d_ws, size_t ws_size,
                              hipStream_t stream) {
  const float* X   = (const float*)d_in[0];
  const float* adj = (const float*)d_in[1];
  const float* W1  = (const float*)d_in[2];
  const float* as1 = (const float*)d_in[3];
  const float* ad1 = (const float*)d_in[4];
  const float* W2  = (const float*)d_in[5];
  const float* as2 = (const float*)d_in[6];
  const float* ad2 = (const float*)d_in[7];
  float* out = (float*)d_out;

  // workspace layout (17 MB total)
  char* ws = (char*)d_ws;
  u16b*  Wt    = (u16b*)ws;                          // 512 KB
  int*   counts= (int*)(ws + (512 << 10));           // 16 KB
  float* src1t = (float*)(ws + (528 << 10));         // 64 KB
  float* dst1t = (float*)(ws + (592 << 10));         // 64 KB
  float* src2  = (float*)(ws + (656 << 10));         // 16 KB
  float* dst2  = (float*)(ws + (672 << 10));         // 16 KB
  float* Wh2   = (float*)(ws + (688 << 10));         // 256 KB
  u16b*  Xbf   = (u16b*)(ws + (1ull << 20));         // 4 MB
  u16b*  Wh1bf = (u16b*)(ws + (5ull << 20));         // 4 MB
  u16b*  csr   = (u16b*)(ws + (9ull << 20));         // 4 MB
  unsigned* h1bf = (unsigned*)(ws + (13ull << 20));  // 4 MB

  k_prep <<<dim3(3072), dim3(256), 0, stream>>>(W1, X, Wt, Xbf);
  k_build<<<dim3(1024), dim3(256), 0, stream>>>(adj, csr, counts);
  k_gemm1<<<dim3(256,8),dim3(256), 0, stream>>>(Xbf, Wt, Wh1bf);
  k_srcdst1<<<dim3(1024),dim3(256),0, stream>>>(Wh1bf, as1, ad1, src1t, dst1t);
  k_attn1<<<dim3(GN),   dim3(256), 0, stream>>>(csr, counts, Wh1bf, src1t, dst1t, h1bf);
  k_gemm2<<<dim3(GN),   dim3(256), 0, stream>>>((const u16b*)h1bf, W2, as2, ad2, Wh2, src2, dst2);
  k_attn2<<<dim3(1024), dim3(256), 0, stream>>>(csr, counts, Wh2, src2, dst2, out);
}

// Round 5
// 69.545 us; speedup vs baseline: 2.6164x; 1.4779x over previous
//
#include <hip/hip_runtime.h>
#include <hip/hip_bf16.h>

// GAT on MI355X. N=4096, DIN=512, H=128, K=4 heads, DOUT=16, p(adj)=0.01.
// 4 dispatches: k_front (CSR build + W1 pack + X->bf16),
//               k_gemm1 (LDS-tiled MFMA, fused src1/dst1 epilogue),
//               k_attn1 (attn + ELU + fused gemm2 -> Wh2/src2/dst2),
//               k_attn2 (attn + log_softmax).

typedef __attribute__((ext_vector_type(4))) float floatx4;
typedef __attribute__((ext_vector_type(8))) short short8;
typedef unsigned short u16b;

#define GN 4096

__device__ __forceinline__ u16b f2bf(float f) {
  union { float f; unsigned int i; } v; v.f = f;
  unsigned int r = v.i + 0x7FFF + ((v.i >> 16) & 1);   // RTN-even
  return (u16b)(r >> 16);
}
__device__ __forceinline__ float bflo(unsigned u) {
  union { unsigned i; float f; } v; v.i = u << 16; return v.f;
}
__device__ __forceinline__ float bfhi(unsigned u) {
  union { unsigned i; float f; } v; v.i = u & 0xffff0000u; return v.f;
}

// ---- K0: fused front. Blocks [0,1024): CSR build (1 wave/row, ballot compaction);
//          [1024,1280): W1 pack (4/thread); [1280,2304): X f32->bf16 (8/thread).
__global__ __launch_bounds__(256) void k_front(const float* __restrict__ adj,
    const float* __restrict__ W1, const float* __restrict__ X,
    u16b* __restrict__ csr, int* __restrict__ counts,
    u16b* __restrict__ Wt, u16b* __restrict__ Xbf) {
  int b = blockIdx.x, t = threadIdx.x;
  if (b < 1024) {
    int w = t >> 6, lane = t & 63;
    int n = b * 4 + w;
    const float* arow = adj + (size_t)n * 4096;
    u16b* row = csr + (size_t)n * 512;
    unsigned long long below = (1ull << lane) - 1ull;
    int run = 0;
#pragma unroll
    for (int ch = 0; ch < 16; ++ch) {
      int m0 = ch * 256 + lane * 4;
      floatx4 v = *(const floatx4*)(arow + m0);
      bool f0 = (v[0] != 0.f) | (m0     == n);
      bool f1 = (v[1] != 0.f) | (m0 + 1 == n);
      bool f2 = (v[2] != 0.f) | (m0 + 2 == n);
      bool f3 = (v[3] != 0.f) | (m0 + 3 == n);
      unsigned long long b0 = __ballot(f0), b1 = __ballot(f1);
      unsigned long long b2 = __ballot(f2), b3 = __ballot(f3);
      int c0 = __popcll(b0), c1 = __popcll(b1), c2 = __popcll(b2);
      if (f0) row[run +            __popcll(b0 & below)] = (u16b)m0;
      if (f1) row[run + c0 +       __popcll(b1 & below)] = (u16b)(m0 + 1);
      if (f2) row[run + c0+c1 +    __popcll(b2 & below)] = (u16b)(m0 + 2);
      if (f3) row[run + c0+c1+c2 + __popcll(b3 & below)] = (u16b)(m0 + 3);
      run += c0 + c1 + c2 + __popcll(b3);
    }
    if (lane == 0) counts[n] = run;
  } else if (b < 1280) {
    int idx = (b - 1024) * 1024 + t * 4;               // 262144 elems, 4/thread
    int c = idx >> 9, i = idx & 511;
    const float* wsrc = W1 + (size_t)(c >> 7) * 65536 + (c & 127);
#pragma unroll
    for (int q = 0; q < 4; ++q)
      Wt[(size_t)c * 512 + i + q] = f2bf(wsrc[(size_t)(i + q) * 128]);
  } else {
    int i0 = ((b - 1280) * 256 + t) * 8;               // 2M elems, 8/thread
    floatx4 v0 = *(const floatx4*)(X + i0);
    floatx4 v1 = *(const floatx4*)(X + i0 + 4);
    short8 o;
    o[0] = (short)f2bf(v0[0]); o[1] = (short)f2bf(v0[1]);
    o[2] = (short)f2bf(v0[2]); o[3] = (short)f2bf(v0[3]);
    o[4] = (short)f2bf(v1[0]); o[5] = (short)f2bf(v1[1]);
    o[6] = (short)f2bf(v1[2]); o[7] = (short)f2bf(v1[3]);
    *(short8*)(Xbf + i0) = o;
  }
}

// ---- K1: Wh1bf = Xbf @ Wt^T per head, 64x128 tile, 512 threads (8 waves 2x4),
//          BK=32 reg-prefetch dbuf, padded LDS (stride 40 shorts = 80B, 16B-aligned).
//          Fused epilogue: src1t/dst1t from f32 accumulators.
#define LDP 40
__global__ __launch_bounds__(512) void k_gemm1(const u16b* __restrict__ Xbf,
    const u16b* __restrict__ Wt, const float* __restrict__ as1,
    const float* __restrict__ ad1, u16b* __restrict__ Wh1bf,
    float* __restrict__ src1t, float* __restrict__ dst1t) {
  int t = threadIdx.x, lane = t & 63, w = t >> 6;
  int wr = w >> 2, wc = w & 3, lh = lane >> 4, lm = lane & 15;
  int rb = blockIdx.x * 64, k = blockIdx.y, cb = k * 128;
  __shared__ u16b Ab[64 * LDP];
  __shared__ u16b Bb[128 * LDP];
  __shared__ float sps[4][64], sds[4][64];
  const u16b* Ag = Xbf + (size_t)(rb + (t >> 2)) * 512 + (t & 3) * 8;  // t<256
  const u16b* Bg = Wt + (size_t)(cb + (t >> 2)) * 512 + (t & 3) * 8;   // all t
  int wo = (t >> 2) * LDP + (t & 3) * 8;
  short8 ra, rbv;
  if (t < 256) ra = *(const short8*)(Ag);
  rbv = *(const short8*)(Bg);
  floatx4 acc[2][2] = {};
#pragma unroll
  for (int kk = 0; kk < 512; kk += 32) {
    if (t < 256) *(short8*)(&Ab[wo]) = ra;
    *(short8*)(&Bb[wo]) = rbv;
    __syncthreads();
    if (kk + 32 < 512) {                       // prefetch next K-step (flies under MFMA)
      if (t < 256) ra = *(const short8*)(Ag + kk + 32);
      rbv = *(const short8*)(Bg + kk + 32);
    }
    short8 a0 = *(const short8*)(&Ab[(wr * 32      + lm) * LDP + lh * 8]);
    short8 a1 = *(const short8*)(&Ab[(wr * 32 + 16 + lm) * LDP + lh * 8]);
    short8 b0 = *(const short8*)(&Bb[(wc * 32      + lm) * LDP + lh * 8]);
    short8 b1 = *(const short8*)(&Bb[(wc * 32 + 16 + lm) * LDP + lh * 8]);
    acc[0][0] = __builtin_amdgcn_mfma_f32_16x16x32_bf16(a0, b0, acc[0][0], 0, 0, 0);
    acc[0][1] = __builtin_amdgcn_mfma_f32_16x16x32_bf16(a0, b1, acc[0][1], 0, 0, 0);
    acc[1][0] = __builtin_amdgcn_mfma_f32_16x16x32_bf16(a1, b0, acc[1][0], 0, 0, 0);
    acc[1][1] = __builtin_amdgcn_mfma_f32_16x16x32_bf16(a1, b1, acc[1][1], 0, 0, 0);
    __syncthreads();
  }
  // C-write: row = rb + wr*32 + m*16 + lh*4 + j, col = cb + wc*32 + n*16 + lm  [m89]
#pragma unroll
  for (int m = 0; m < 2; ++m)
#pragma unroll
    for (int n = 0; n < 2; ++n)
#pragma unroll
      for (int j = 0; j < 4; ++j)
        Wh1bf[(size_t)(rb + wr * 32 + m * 16 + lh * 4 + j) * 512 + cb + wc * 32 + n * 16 + lm]
            = f2bf(acc[m][n][j]);
  // fused src/dst: block covers full head k for its 64 rows
  float asv[2], adv[2];
#pragma unroll
  for (int n = 0; n < 2; ++n) {
    asv[n] = as1[k * 128 + wc * 32 + n * 16 + lm];
    adv[n] = ad1[k * 128 + wc * 32 + n * 16 + lm];
  }
#pragma unroll
  for (int m = 0; m < 2; ++m)
#pragma unroll
    for (int j = 0; j < 4; ++j) {
      float ps = acc[m][0][j] * asv[0] + acc[m][1][j] * asv[1];
      float pd = acc[m][0][j] * adv[0] + acc[m][1][j] * adv[1];
#pragma unroll
      for (int off = 8; off >= 1; off >>= 1) {
        ps += __shfl_xor(ps, off, 16);
        pd += __shfl_xor(pd, off, 16);
      }
      if (lm == 0) {
        sps[wc][wr * 32 + m * 16 + lh * 4 + j] = ps;
        sds[wc][wr * 32 + m * 16 + lh * 4 + j] = pd;
      }
    }
  __syncthreads();
  if (t < 64) {
    src1t[(size_t)(rb + t) * 4 + k] = sps[0][t] + sps[1][t] + sps[2][t] + sps[3][t];
    dst1t[(size_t)(rb + t) * 4 + k] = sds[0][t] + sds[1][t] + sds[2][t] + sds[3][t];
  }
}

// ---- K2: layer-1 attention + ELU + fused layer-2 projection. One block per row n.
__global__ __launch_bounds__(256) void k_attn1(const u16b* __restrict__ csr,
    const int* __restrict__ counts, const u16b* __restrict__ Wh1bf,
    const float* __restrict__ src1t, const float* __restrict__ dst1t,
    const float* __restrict__ W2, const float* __restrict__ as2,
    const float* __restrict__ ad2, float* __restrict__ Wh2,
    float* __restrict__ src2, float* __restrict__ dst2) {
  int n = blockIdx.x, t = threadIdx.x, lane = t & 63, w = t >> 6;
  __shared__ u16b lst[512];
  __shared__ float ew[4][516];
  __shared__ float h1row[512];
  __shared__ float red[256];
  int cnt = counts[n];
  const u16b* row = csr + (size_t)n * 512;
  for (int i = t; i < cnt; i += 256) lst[i] = row[i];
  float sn[4];
#pragma unroll
  for (int k = 0; k < 4; ++k) sn[k] = src1t[n * 4 + k];
  __syncthreads();
  // leaky-relu logits: thread j -> (li=j>>2, k=j&3)
  for (int j = t; j < cnt * 4; j += 256) {
    int li = j >> 2, k = j & 3;
    int m = lst[li];
    float e = sn[k] + dst1t[m * 4 + k];
    ew[k][li] = e > 0.f ? e : 0.2f * e;
  }
  __syncthreads();
  // per-wave softmax over head w, normalize in place
  {
    float mx = -1e30f, sm = 0.f;
    for (int li = lane; li < cnt; li += 64) {
      float e = ew[w][li];
      if (e > mx) { sm = sm * __expf(mx - e) + 1.f; mx = e; }
      else sm += __expf(e - mx);
    }
#pragma unroll
    for (int off = 32; off >= 1; off >>= 1) {
      float mo = __shfl_xor(mx, off);
      float so = __shfl_xor(sm, off);
      float M = fmaxf(mx, mo);
      sm = sm * __expf(mx - M) + so * __expf(mo - M);
      mx = M;
    }
    float R = 1.f / sm;
    for (int li = lane; li < cnt; li += 64)
      ew[w][li] = __expf(ew[w][li] - mx) * R;
  }
  __syncthreads();
  // weighted gather: thread t owns cols 2t,2t+1 (head == w)
  float a0 = 0.f, a1 = 0.f;
  const float* ewk = ew[w];
#pragma unroll 4
  for (int li = 0; li < cnt; ++li) {
    int m = lst[li];
    float wv = ewk[li];
    unsigned u = *(const unsigned*)(Wh1bf + (size_t)m * 512 + 2 * t);
    a0 = fmaf(wv, bflo(u), a0);
    a1 = fmaf(wv, bfhi(u), a1);
  }
  a0 = a0 > 0.f ? a0 : __expf(a0) - 1.f;       // ELU
  a1 = a1 > 0.f ? a1 : __expf(a1) - 1.f;
  h1row[2 * t] = a0;
  h1row[2 * t + 1] = a1;
  __syncthreads();
  // fused layer-2 projection: Wh2[n][o] = h1row . W2[:,o], + src2/dst2
  int o = t & 15, ib = t >> 4;
  float accw = 0.f;
  for (int i = ib; i < 512; i += 16)
    accw = fmaf(h1row[i], W2[i * 16 + o], accw);
  red[t] = accw;
  __syncthreads();
  for (int s = 128; s >= 16; s >>= 1) {
    if (t < s) red[t] += red[t + s];
    __syncthreads();
  }
  if (t < 16) {
    float v = red[t];
    Wh2[n * 16 + t] = v;
    float ps = v * as2[t];
    float pd = v * ad2[t];
#pragma unroll
    for (int off = 8; off >= 1; off >>= 1) {
      ps += __shfl_xor(ps, off, 16);
      pd += __shfl_xor(pd, off, 16);
    }
    if (t == 0) { src2[n] = ps; dst2[n] = pd; }
  }
}

// ---- K3: layer-2 attention + log_softmax. One wave per row (4 rows/block).
__global__ __launch_bounds__(256) void k_attn2(const u16b* __restrict__ csr,
    const int* __restrict__ counts, const float* __restrict__ Wh2,
    const float* __restrict__ src2, const float* __restrict__ dst2,
    float* __restrict__ out) {
  int w = threadIdx.x >> 6, lane = threadIdx.x & 63;
  int n = blockIdx.x * 4 + w;
  int cnt = counts[n];
  const u16b* row = csr + (size_t)n * 512;
  float snv = src2[n];
  float mx = -1e30f, sm = 0.f;
  for (int li = lane; li < cnt; li += 64) {
    int m = row[li];
    float e = snv + dst2[m]; e = e > 0.f ? e : 0.2f * e;
    if (e > mx) { sm = sm * __expf(mx - e) + 1.f; mx = e; }
    else sm += __expf(e - mx);
  }
#pragma unroll
  for (int off = 32; off >= 1; off >>= 1) {
    float mo = __shfl_xor(mx, off);
    float so = __shfl_xor(sm, off);
    float M = fmaxf(mx, mo);
    sm = sm * __expf(mx - M) + so * __expf(mo - M);
    mx = M;
  }
  float R = 1.f / sm;
  int o = lane & 15, g = lane >> 4;
  float acc = 0.f;
  for (int li = g; li < cnt; li += 4) {
    int m = row[li];
    float e = snv + dst2[m]; e = e > 0.f ? e : 0.2f * e;
    float wgt = __expf(e - mx) * R;
    acc = fmaf(wgt, Wh2[m * 16 + o], acc);
  }
  acc += __shfl_xor(acc, 16);
  acc += __shfl_xor(acc, 32);
  float vm = acc;
#pragma unroll
  for (int off = 8; off >= 1; off >>= 1) vm = fmaxf(vm, __shfl_xor(vm, off, 16));
  float ex = __expf(acc - vm);
#pragma unroll
  for (int off = 8; off >= 1; off >>= 1) ex += __shfl_xor(ex, off, 16);
  if (lane < 16) out[(size_t)n * 16 + lane] = acc - vm - __logf(ex);
}

extern "C" void kernel_launch(void* const* d_in, const int* in_sizes, int n_in,
                              void* d_out, int out_size, void* d_ws, size_t ws_size,
                              hipStream_t stream) {
  const float* X   = (const float*)d_in[0];
  const float* adj = (const float*)d_in[1];
  const float* W1  = (const float*)d_in[2];
  const float* as1 = (const float*)d_in[3];
  const float* ad1 = (const float*)d_in[4];
  const float* W2  = (const float*)d_in[5];
  const float* as2 = (const float*)d_in[6];
  const float* ad2 = (const float*)d_in[7];
  float* out = (float*)d_out;

  // workspace (13 MB)
  char* ws = (char*)d_ws;
  u16b*  Wt    = (u16b*)ws;                          // 512 KB  bf16 [c][i]
  int*   counts= (int*)(ws + (512 << 10));           // 16 KB
  float* src1t = (float*)(ws + (528 << 10));         // 64 KB   [n][k]
  float* dst1t = (float*)(ws + (592 << 10));         // 64 KB   [n][k]
  float* src2  = (float*)(ws + (656 << 10));         // 16 KB
  float* dst2  = (float*)(ws + (672 << 10));         // 16 KB
  float* Wh2   = (float*)(ws + (688 << 10));         // 256 KB
  u16b*  Xbf   = (u16b*)(ws + (1ull << 20));         // 4 MB
  u16b*  Wh1bf = (u16b*)(ws + (5ull << 20));         // 4 MB
  u16b*  csr   = (u16b*)(ws + (9ull << 20));         // 4 MB

  k_front<<<dim3(2304), dim3(256), 0, stream>>>(adj, W1, X, csr, counts, Wt, Xbf);
  k_gemm1<<<dim3(64, 4), dim3(512), 0, stream>>>(Xbf, Wt, as1, ad1, Wh1bf, src1t, dst1t);
  k_attn1<<<dim3(GN), dim3(256), 0, stream>>>(csr, counts, Wh1bf, src1t, dst1t,
                                              W2, as2, ad2, Wh2, src2, dst2);
  k_attn2<<<dim3(1024), dim3(256), 0, stream>>>(csr, counts, Wh2, src2, dst2, out);
}

// Round 6
// 68.426 us; speedup vs baseline: 2.6591x; 1.0164x over previous
//
#include <hip/hip_runtime.h>
#include <hip/hip_bf16.h>

// GAT on MI355X. N=4096, DIN=512, H=128, K=4 heads, DOUT=16, p(adj)=0.01.
// 3 dispatches:
//   k_fused1: CSR build (512 blocks, HBM-bound) ∥ gemm1 (256 blocks, MFMA,
//             inline f32->bf16 convert + in-reg B transpose, fused src1/dst1).
//   k_attn1:  layer-1 attn + ELU + fused layer-2 projection (Wh2/src2/dst2).
//   k_attn2:  layer-2 attn + log_softmax.

typedef __attribute__((ext_vector_type(4))) float floatx4;
typedef __attribute__((ext_vector_type(8))) short short8;
typedef __attribute__((ext_vector_type(4))) unsigned short ushortx4;
typedef unsigned short u16b;

#define GN 4096
#define LDP 40   // LDS row stride in shorts (80B, keeps b64/b128 writes/reads aligned)

__device__ __forceinline__ u16b f2bf(float f) {
  union { float f; unsigned int i; } v; v.f = f;
  unsigned int r = v.i + 0x7FFF + ((v.i >> 16) & 1);   // RTN-even
  return (u16b)(r >> 16);
}
__device__ __forceinline__ float bflo(unsigned u) {
  union { unsigned i; float f; } v; v.i = u << 16; return v.f;
}
__device__ __forceinline__ float bfhi(unsigned u) {
  union { unsigned i; float f; } v; v.i = u & 0xffff0000u; return v.f;
}

// ---- D1: blocks [0,512): CSR build, 1 wave/row (8 rows/block).
//          blocks [512,768): gemm1 64x128 tile (row-panel x head), fused src1/dst1.
__global__ __launch_bounds__(512) void k_fused1(const float* __restrict__ adj,
    const float* __restrict__ X, const float* __restrict__ W1,
    const float* __restrict__ as1, const float* __restrict__ ad1,
    u16b* __restrict__ csr, int* __restrict__ counts,
    u16b* __restrict__ Wh1bf, float* __restrict__ src1t, float* __restrict__ dst1t) {
  int b = blockIdx.x, t = threadIdx.x;
  int lane = t & 63, w = t >> 6;
  if (b < 512) {
    // ---------------- CSR build ----------------
    int n = b * 8 + w;
    const float* arow = adj + (size_t)n * 4096;
    u16b* row = csr + (size_t)n * 512;
    unsigned long long below = (1ull << lane) - 1ull;
    int run = 0;
#pragma unroll
    for (int ch = 0; ch < 16; ++ch) {
      int m0 = ch * 256 + lane * 4;
      floatx4 v = *(const floatx4*)(arow + m0);
      bool f0 = (v[0] != 0.f) | (m0     == n);
      bool f1 = (v[1] != 0.f) | (m0 + 1 == n);
      bool f2 = (v[2] != 0.f) | (m0 + 2 == n);
      bool f3 = (v[3] != 0.f) | (m0 + 3 == n);
      unsigned long long b0 = __ballot(f0), b1 = __ballot(f1);
      unsigned long long b2 = __ballot(f2), b3 = __ballot(f3);
      int c0 = __popcll(b0), c1 = __popcll(b1), c2 = __popcll(b2);
      if (f0) row[run +            __popcll(b0 & below)] = (u16b)m0;
      if (f1) row[run + c0 +       __popcll(b1 & below)] = (u16b)(m0 + 1);
      if (f2) row[run + c0+c1 +    __popcll(b2 & below)] = (u16b)(m0 + 2);
      if (f3) row[run + c0+c1+c2 + __popcll(b3 & below)] = (u16b)(m0 + 3);
      run += c0 + c1 + c2 + __popcll(b3);
    }
    if (lane == 0) counts[n] = run;
  } else {
    // ---------------- gemm1 ----------------
    __shared__ u16b Ab[64 * LDP];
    __shared__ u16b Bb[128 * LDP];
    __shared__ float sps[4][64], sds[4][64];
    int gb = b - 512;
    int rb = (gb >> 2) * 64, hd = gb & 3;
    const float* Wk = W1 + (size_t)hd * 65536;
    int wr = w >> 2, wc = w & 3, lh = lane >> 4, lm = lane & 15;
    // staging roles: t<256 stage A (X f32 -> bf16); t>=256 stage B (W1 transpose)
    int ar = t >> 1, aq = t & 1;                    // unused half below; real mapping:
    ar = t >> 2; aq = t & 3;                         // A: row=t>>2, 8-col quad=t&3
    int u = t - 256, kk0 = (u & 7) * 4, c0 = (u >> 3) * 4;  // B: 4kk x 4c subtile
    floatx4 pa0, pa1, pb0, pb1, pb2, pb3;
    if (t < 256) {
      const float* ap = X + (size_t)(rb + ar) * 512 + aq * 8;
      pa0 = *(const floatx4*)(ap);
      pa1 = *(const floatx4*)(ap + 4);
    } else {
      const float* bp = Wk + (size_t)kk0 * 128 + c0;
      pb0 = *(const floatx4*)(bp);
      pb1 = *(const floatx4*)(bp + 128);
      pb2 = *(const floatx4*)(bp + 256);
      pb3 = *(const floatx4*)(bp + 384);
    }
    floatx4 acc[2][2] = {};
    for (int kk = 0; kk < 512; kk += 32) {
      if (t < 256) {
        short8 a;
        a[0] = (short)f2bf(pa0[0]); a[1] = (short)f2bf(pa0[1]);
        a[2] = (short)f2bf(pa0[2]); a[3] = (short)f2bf(pa0[3]);
        a[4] = (short)f2bf(pa1[0]); a[5] = (short)f2bf(pa1[1]);
        a[6] = (short)f2bf(pa1[2]); a[7] = (short)f2bf(pa1[3]);
        *(short8*)(&Ab[ar * LDP + aq * 8]) = a;
      } else {
#pragma unroll
        for (int cq = 0; cq < 4; ++cq) {
          ushortx4 v;
          v[0] = f2bf(pb0[cq]); v[1] = f2bf(pb1[cq]);
          v[2] = f2bf(pb2[cq]); v[3] = f2bf(pb3[cq]);
          *(ushortx4*)(&Bb[(c0 + cq) * LDP + kk0]) = v;   // Bb[c][kk']
        }
      }
      __syncthreads();
      if (kk + 32 < 512) {                           // prefetch next K-step
        if (t < 256) {
          const float* ap = X + (size_t)(rb + ar) * 512 + kk + 32 + aq * 8;
          pa0 = *(const floatx4*)(ap);
          pa1 = *(const floatx4*)(ap + 4);
        } else {
          const float* bp = Wk + (size_t)(kk + 32 + kk0) * 128 + c0;
          pb0 = *(const floatx4*)(bp);
          pb1 = *(const floatx4*)(bp + 128);
          pb2 = *(const floatx4*)(bp + 256);
          pb3 = *(const floatx4*)(bp + 384);
        }
      }
      short8 a0 = *(const short8*)(&Ab[(wr * 32      + lm) * LDP + lh * 8]);
      short8 a1 = *(const short8*)(&Ab[(wr * 32 + 16 + lm) * LDP + lh * 8]);
      short8 b0 = *(const short8*)(&Bb[(wc * 32      + lm) * LDP + lh * 8]);
      short8 b1 = *(const short8*)(&Bb[(wc * 32 + 16 + lm) * LDP + lh * 8]);
      acc[0][0] = __builtin_amdgcn_mfma_f32_16x16x32_bf16(a0, b0, acc[0][0], 0, 0, 0);
      acc[0][1] = __builtin_amdgcn_mfma_f32_16x16x32_bf16(a0, b1, acc[0][1], 0, 0, 0);
      acc[1][0] = __builtin_amdgcn_mfma_f32_16x16x32_bf16(a1, b0, acc[1][0], 0, 0, 0);
      acc[1][1] = __builtin_amdgcn_mfma_f32_16x16x32_bf16(a1, b1, acc[1][1], 0, 0, 0);
      __syncthreads();
    }
    // C-write: row = rb + wr*32 + m*16 + lh*4 + j, col = hd*128 + wc*32 + n*16 + lm  [m89]
#pragma unroll
    for (int m = 0; m < 2; ++m)
#pragma unroll
      for (int n2 = 0; n2 < 2; ++n2)
#pragma unroll
        for (int j = 0; j < 4; ++j)
          Wh1bf[(size_t)(rb + wr * 32 + m * 16 + lh * 4 + j) * 512
                + hd * 128 + wc * 32 + n2 * 16 + lm] = f2bf(acc[m][n2][j]);
    // fused src/dst epilogue (block covers full head hd for its 64 rows)
    float asv[2], adv[2];
#pragma unroll
    for (int n2 = 0; n2 < 2; ++n2) {
      asv[n2] = as1[hd * 128 + wc * 32 + n2 * 16 + lm];
      adv[n2] = ad1[hd * 128 + wc * 32 + n2 * 16 + lm];
    }
#pragma unroll
    for (int m = 0; m < 2; ++m)
#pragma unroll
      for (int j = 0; j < 4; ++j) {
        float ps = acc[m][0][j] * asv[0] + acc[m][1][j] * asv[1];
        float pd = acc[m][0][j] * adv[0] + acc[m][1][j] * adv[1];
#pragma unroll
        for (int off = 8; off >= 1; off >>= 1) {
          ps += __shfl_xor(ps, off, 16);
          pd += __shfl_xor(pd, off, 16);
        }
        if (lm == 0) {
          sps[wc][wr * 32 + m * 16 + lh * 4 + j] = ps;
          sds[wc][wr * 32 + m * 16 + lh * 4 + j] = pd;
        }
      }
    __syncthreads();
    if (t < 64) {
      src1t[(size_t)(rb + t) * 4 + hd] = sps[0][t] + sps[1][t] + sps[2][t] + sps[3][t];
      dst1t[(size_t)(rb + t) * 4 + hd] = sds[0][t] + sds[1][t] + sds[2][t] + sds[3][t];
    }
  }
}

// ---- D2: layer-1 attention + ELU + fused layer-2 projection. One block per row n.
__global__ __launch_bounds__(256) void k_attn1(const u16b* __restrict__ csr,
    const int* __restrict__ counts, const u16b* __restrict__ Wh1bf,
    const float* __restrict__ src1t, const float* __restrict__ dst1t,
    const float* __restrict__ W2, const float* __restrict__ as2,
    const float* __restrict__ ad2, float* __restrict__ Wh2,
    float* __restrict__ src2, float* __restrict__ dst2) {
  int n = blockIdx.x, t = threadIdx.x, lane = t & 63, w = t >> 6;
  __shared__ u16b lst[512];
  __shared__ float ew[4][516];
  __shared__ float h1row[512];
  __shared__ float redw[4][16];
  int cnt = counts[n];
  const u16b* row = csr + (size_t)n * 512;
  for (int i = t; i < cnt; i += 256) lst[i] = row[i];
  float sn[4];
#pragma unroll
  for (int k = 0; k < 4; ++k) sn[k] = src1t[n * 4 + k];
  __syncthreads();
  // leaky-relu logits: thread j -> (li=j>>2, k=j&3); 4 consecutive threads share 16B dst1t
  for (int j = t; j < cnt * 4; j += 256) {
    int li = j >> 2, k = j & 3;
    int m = lst[li];
    float e = sn[k] + dst1t[m * 4 + k];
    ew[k][li] = e > 0.f ? e : 0.2f * e;
  }
  __syncthreads();
  // per-wave softmax over head w, normalize in place
  {
    float mx = -1e30f, sm = 0.f;
    for (int li = lane; li < cnt; li += 64) {
      float e = ew[w][li];
      if (e > mx) { sm = sm * __expf(mx - e) + 1.f; mx = e; }
      else sm += __expf(e - mx);
    }
#pragma unroll
    for (int off = 32; off >= 1; off >>= 1) {
      float mo = __shfl_xor(mx, off);
      float so = __shfl_xor(sm, off);
      float M = fmaxf(mx, mo);
      sm = sm * __expf(mx - M) + so * __expf(mo - M);
      mx = M;
    }
    float R = 1.f / sm;
    for (int li = lane; li < cnt; li += 64)
      ew[w][li] = __expf(ew[w][li] - mx) * R;
  }
  __syncthreads();
  // weighted gather: thread t owns cols 2t, 2t+1 (head == w)
  float a0 = 0.f, a1 = 0.f;
  const float* ewk = ew[w];
#pragma unroll 4
  for (int li = 0; li < cnt; ++li) {
    int m = lst[li];
    float wv = ewk[li];
    unsigned uu = *(const unsigned*)(Wh1bf + (size_t)m * 512 + 2 * t);
    a0 = fmaf(wv, bflo(uu), a0);
    a1 = fmaf(wv, bfhi(uu), a1);
  }
  a0 = a0 > 0.f ? a0 : __expf(a0) - 1.f;       // ELU
  a1 = a1 > 0.f ? a1 : __expf(a1) - 1.f;
  h1row[2 * t] = a0;
  h1row[2 * t + 1] = a1;
  __syncthreads();
  // fused layer-2 projection: per-wave partial over i in [w*128,(w+1)*128)
  {
    int o = lane & 15, ig = lane >> 4;
    float accw = 0.f;
    for (int i = w * 128 + ig; i < (w + 1) * 128; i += 4)
      accw = fmaf(h1row[i], W2[i * 16 + o], accw);
    accw += __shfl_xor(accw, 16);
    accw += __shfl_xor(accw, 32);
    if (lane < 16) redw[w][o] = accw;
  }
  __syncthreads();
  if (t < 16) {
    float v = redw[0][t] + redw[1][t] + redw[2][t] + redw[3][t];
    Wh2[n * 16 + t] = v;
    float ps = v * as2[t];
    float pd = v * ad2[t];
#pragma unroll
    for (int off = 8; off >= 1; off >>= 1) {
      ps += __shfl_xor(ps, off, 16);
      pd += __shfl_xor(pd, off, 16);
    }
    if (t == 0) { src2[n] = ps; dst2[n] = pd; }
  }
}

// ---- D3: layer-2 attention + log_softmax. One wave per row (4 rows/block).
__global__ __launch_bounds__(256) void k_attn2(const u16b* __restrict__ csr,
    const int* __restrict__ counts, const float* __restrict__ Wh2,
    const float* __restrict__ src2, const float* __restrict__ dst2,
    float* __restrict__ out) {
  int w = threadIdx.x >> 6, lane = threadIdx.x & 63;
  int n = blockIdx.x * 4 + w;
  int cnt = counts[n];
  const u16b* row = csr + (size_t)n * 512;
  float snv = src2[n];
  float mx = -1e30f, sm = 0.f;
  for (int li = lane; li < cnt; li += 64) {
    int m = row[li];
    float e = snv + dst2[m]; e = e > 0.f ? e : 0.2f * e;
    if (e > mx) { sm = sm * __expf(mx - e) + 1.f; mx = e; }
    else sm += __expf(e - mx);
  }
#pragma unroll
  for (int off = 32; off >= 1; off >>= 1) {
    float mo = __shfl_xor(mx, off);
    float so = __shfl_xor(sm, off);
    float M = fmaxf(mx, mo);
    sm = sm * __expf(mx - M) + so * __expf(mo - M);
    mx = M;
  }
  float R = 1.f / sm;
  int o = lane & 15, g = lane >> 4;
  float acc = 0.f;
  for (int li = g; li < cnt; li += 4) {
    int m = row[li];
    float e = snv + dst2[m]; e = e > 0.f ? e : 0.2f * e;
    float wgt = __expf(e - mx) * R;
    acc = fmaf(wgt, Wh2[m * 16 + o], acc);
  }
  acc += __shfl_xor(acc, 16);
  acc += __shfl_xor(acc, 32);
  float vm = acc;
#pragma unroll
  for (int off = 8; off >= 1; off >>= 1) vm = fmaxf(vm, __shfl_xor(vm, off, 16));
  float ex = __expf(acc - vm);
#pragma unroll
  for (int off = 8; off >= 1; off >>= 1) ex += __shfl_xor(ex, off, 16);
  if (lane < 16) out[(size_t)n * 16 + lane] = acc - vm - __logf(ex);
}

extern "C" void kernel_launch(void* const* d_in, const int* in_sizes, int n_in,
                              void* d_out, int out_size, void* d_ws, size_t ws_size,
                              hipStream_t stream) {
  const float* X   = (const float*)d_in[0];
  const float* adj = (const float*)d_in[1];
  const float* W1  = (const float*)d_in[2];
  const float* as1 = (const float*)d_in[3];
  const float* ad1 = (const float*)d_in[4];
  const float* W2  = (const float*)d_in[5];
  const float* as2 = (const float*)d_in[6];
  const float* ad2 = (const float*)d_in[7];
  float* out = (float*)d_out;

  // workspace (9 MB)
  char* ws = (char*)d_ws;
  int*   counts= (int*)ws;                           // 16 KB
  float* src1t = (float*)(ws + (16 << 10));          // 64 KB   [n][k]
  float* dst1t = (float*)(ws + (80 << 10));          // 64 KB   [n][k]
  float* src2  = (float*)(ws + (144 << 10));         // 16 KB
  float* dst2  = (float*)(ws + (160 << 10));         // 16 KB
  float* Wh2   = (float*)(ws + (176 << 10));         // 256 KB
  u16b*  Wh1bf = (u16b*)(ws + (1ull << 20));         // 4 MB
  u16b*  csr   = (u16b*)(ws + (5ull << 20));         // 4 MB

  k_fused1<<<dim3(768), dim3(512), 0, stream>>>(adj, X, W1, as1, ad1,
                                                csr, counts, Wh1bf, src1t, dst1t);
  k_attn1<<<dim3(GN), dim3(256), 0, stream>>>(csr, counts, Wh1bf, src1t, dst1t,
                                              W2, as2, ad2, Wh2, src2, dst2);
  k_attn2<<<dim3(1024), dim3(256), 0, stream>>>(csr, counts, Wh2, src2, dst2, out);
}

// Round 7
// 67.000 us; speedup vs baseline: 2.7158x; 1.0213x over previous
//
#include <hip/hip_runtime.h>
#include <hip/hip_bf16.h>

// GAT on MI355X. N=4096, DIN=512, H=128, K=4 heads, DOUT=16, p(adj)=0.01.
// 3 dispatches:
//   D1 k_fused1: [0,256) gemm1 (MFMA, XCD-grouped panels, fused src1/dst1)
//                [256,2304) adj->bitmask (pure streaming, 16 bits/thread).
//   D2 k_attn1:  decode mask row -> attn + ELU + fused layer-2 projection.
//   D3 k_attn2:  decode mask row -> attn + log_softmax.

typedef __attribute__((ext_vector_type(4))) float floatx4;
typedef __attribute__((ext_vector_type(8))) short short8;
typedef __attribute__((ext_vector_type(4))) unsigned short ushortx4;
typedef unsigned short u16b;

#define GN 4096
#define LDP 40   // LDS row stride in shorts (80B)

__device__ __forceinline__ u16b f2bf(float f) {
  union { float f; unsigned int i; } v; v.f = f;
  unsigned int r = v.i + 0x7FFF + ((v.i >> 16) & 1);   // RTN-even
  return (u16b)(r >> 16);
}
__device__ __forceinline__ float bflo(unsigned u) {
  union { unsigned i; float f; } v; v.i = u << 16; return v.f;
}
__device__ __forceinline__ float bfhi(unsigned u) {
  union { unsigned i; float f; } v; v.i = u & 0xffff0000u; return v.f;
}

// ---- D1: gemm1 (blocks 0..255) || bitmask build (blocks 256..2303).
__global__ __launch_bounds__(512) void k_fused1(const float* __restrict__ adj,
    const float* __restrict__ X, const float* __restrict__ W1,
    const float* __restrict__ as1, const float* __restrict__ ad1,
    u16b* __restrict__ mask, u16b* __restrict__ Wh1bf,
    float* __restrict__ src1t, float* __restrict__ dst1t) {
  int b = blockIdx.x, t = threadIdx.x;
  int lane = t & 63, w = t >> 6;
  if (b >= 256) {
    // ---------------- bitmask build: 2 rows per block, 16 cols/thread ----------
    int n = (b - 256) * 2 + (t >> 8);
    int cg = t & 255;                       // u16 col-group
    const float* ap = adj + (size_t)n * 4096 + cg * 16;
    floatx4 v0 = *(const floatx4*)(ap);
    floatx4 v1 = *(const floatx4*)(ap + 4);
    floatx4 v2 = *(const floatx4*)(ap + 8);
    floatx4 v3 = *(const floatx4*)(ap + 12);
    unsigned bits = 0;
#pragma unroll
    for (int i = 0; i < 4; ++i) {
      bits |= (unsigned)(v0[i] != 0.f) << i;
      bits |= (unsigned)(v1[i] != 0.f) << (4 + i);
      bits |= (unsigned)(v2[i] != 0.f) << (8 + i);
      bits |= (unsigned)(v3[i] != 0.f) << (12 + i);
    }
    if ((n >> 4) == cg) bits |= 1u << (n & 15);        // self-loop
    mask[(size_t)n * 256 + cg] = (u16b)bits;
  } else {
    // ---------------- gemm1: panel p, head hd; all 4 heads of p share an XCD ----
    __shared__ u16b Ab[64 * LDP];
    __shared__ u16b Bb[128 * LDP];
    __shared__ float sps[4][64], sds[4][64];
    int p = ((b >> 5) << 3) | (b & 7);
    int hd = (b >> 3) & 3;
    int rb = p * 64;
    const float* Wk = W1 + (size_t)hd * 65536;
    int wr = w >> 2, wc = w & 3, lh = lane >> 4, lm = lane & 15;
    int ar = t >> 2, aq = t & 3;                             // A: row, 8-col quad
    int u = t - 256, kk0 = (u & 7) * 4, c0 = (u >> 3) * 4;   // B: 4kk x 4c subtile
    floatx4 pa0, pa1, pb0, pb1, pb2, pb3;
    if (t < 256) {
      const float* ap = X + (size_t)(rb + ar) * 512 + aq * 8;
      pa0 = *(const floatx4*)(ap);
      pa1 = *(const floatx4*)(ap + 4);
    } else {
      const float* bp = Wk + (size_t)kk0 * 128 + c0;
      pb0 = *(const floatx4*)(bp);
      pb1 = *(const floatx4*)(bp + 128);
      pb2 = *(const floatx4*)(bp + 256);
      pb3 = *(const floatx4*)(bp + 384);
    }
    floatx4 acc[2][2] = {};
    for (int kk = 0; kk < 512; kk += 32) {
      if (t < 256) {
        short8 a;
        a[0] = (short)f2bf(pa0[0]); a[1] = (short)f2bf(pa0[1]);
        a[2] = (short)f2bf(pa0[2]); a[3] = (short)f2bf(pa0[3]);
        a[4] = (short)f2bf(pa1[0]); a[5] = (short)f2bf(pa1[1]);
        a[6] = (short)f2bf(pa1[2]); a[7] = (short)f2bf(pa1[3]);
        *(short8*)(&Ab[ar * LDP + aq * 8]) = a;
      } else {
#pragma unroll
        for (int cq = 0; cq < 4; ++cq) {
          ushortx4 v;
          v[0] = f2bf(pb0[cq]); v[1] = f2bf(pb1[cq]);
          v[2] = f2bf(pb2[cq]); v[3] = f2bf(pb3[cq]);
          *(ushortx4*)(&Bb[(c0 + cq) * LDP + kk0]) = v;     // Bb[c][kk']
        }
      }
      __syncthreads();
      if (kk + 32 < 512) {                                   // prefetch next K-step
        if (t < 256) {
          const float* ap = X + (size_t)(rb + ar) * 512 + kk + 32 + aq * 8;
          pa0 = *(const floatx4*)(ap);
          pa1 = *(const floatx4*)(ap + 4);
        } else {
          const float* bp = Wk + (size_t)(kk + 32 + kk0) * 128 + c0;
          pb0 = *(const floatx4*)(bp);
          pb1 = *(const floatx4*)(bp + 128);
          pb2 = *(const floatx4*)(bp + 256);
          pb3 = *(const floatx4*)(bp + 384);
        }
      }
      short8 a0 = *(const short8*)(&Ab[(wr * 32      + lm) * LDP + lh * 8]);
      short8 a1 = *(const short8*)(&Ab[(wr * 32 + 16 + lm) * LDP + lh * 8]);
      short8 b0 = *(const short8*)(&Bb[(wc * 32      + lm) * LDP + lh * 8]);
      short8 b1 = *(const short8*)(&Bb[(wc * 32 + 16 + lm) * LDP + lh * 8]);
      acc[0][0] = __builtin_amdgcn_mfma_f32_16x16x32_bf16(a0, b0, acc[0][0], 0, 0, 0);
      acc[0][1] = __builtin_amdgcn_mfma_f32_16x16x32_bf16(a0, b1, acc[0][1], 0, 0, 0);
      acc[1][0] = __builtin_amdgcn_mfma_f32_16x16x32_bf16(a1, b0, acc[1][0], 0, 0, 0);
      acc[1][1] = __builtin_amdgcn_mfma_f32_16x16x32_bf16(a1, b1, acc[1][1], 0, 0, 0);
      __syncthreads();
    }
    // C-write: row = rb + wr*32 + m*16 + lh*4 + j, col = hd*128 + wc*32 + n*16 + lm
#pragma unroll
    for (int m = 0; m < 2; ++m)
#pragma unroll
      for (int n2 = 0; n2 < 2; ++n2)
#pragma unroll
        for (int j = 0; j < 4; ++j)
          Wh1bf[(size_t)(rb + wr * 32 + m * 16 + lh * 4 + j) * 512
                + hd * 128 + wc * 32 + n2 * 16 + lm] = f2bf(acc[m][n2][j]);
    // fused src/dst epilogue
    float asv[2], adv[2];
#pragma unroll
    for (int n2 = 0; n2 < 2; ++n2) {
      asv[n2] = as1[hd * 128 + wc * 32 + n2 * 16 + lm];
      adv[n2] = ad1[hd * 128 + wc * 32 + n2 * 16 + lm];
    }
#pragma unroll
    for (int m = 0; m < 2; ++m)
#pragma unroll
      for (int j = 0; j < 4; ++j) {
        float ps = acc[m][0][j] * asv[0] + acc[m][1][j] * asv[1];
        float pd = acc[m][0][j] * adv[0] + acc[m][1][j] * adv[1];
#pragma unroll
        for (int off = 8; off >= 1; off >>= 1) {
          ps += __shfl_xor(ps, off, 16);
          pd += __shfl_xor(pd, off, 16);
        }
        if (lm == 0) {
          sps[wc][wr * 32 + m * 16 + lh * 4 + j] = ps;
          sds[wc][wr * 32 + m * 16 + lh * 4 + j] = pd;
        }
      }
    __syncthreads();
    if (t < 64) {
      src1t[(size_t)(rb + t) * 4 + hd] = sps[0][t] + sps[1][t] + sps[2][t] + sps[3][t];
      dst1t[(size_t)(rb + t) * 4 + hd] = sds[0][t] + sds[1][t] + sds[2][t] + sds[3][t];
    }
  }
}

// ---- D2: decode mask + layer-1 attention + ELU + fused layer-2 projection.
__global__ __launch_bounds__(256) void k_attn1(const u16b* __restrict__ mask,
    const u16b* __restrict__ Wh1bf,
    const float* __restrict__ src1t, const float* __restrict__ dst1t,
    const float* __restrict__ W2, const float* __restrict__ as2,
    const float* __restrict__ ad2, float* __restrict__ Wh2,
    float* __restrict__ src2, float* __restrict__ dst2) {
  int n = blockIdx.x, t = threadIdx.x, lane = t & 63, w = t >> 6;
  __shared__ u16b lst[512];
  __shared__ float ew[4][516];
  __shared__ float h1row[512];
  __shared__ float redw[4][16];
  __shared__ int wtot[4];
  // ---- decode: thread t owns cols [16t,16t+16)
  unsigned M = mask[(size_t)n * 256 + t];
  int pc = __popc(M);
  int incl = pc;
#pragma unroll
  for (int off = 1; off <= 32; off <<= 1) {
    int v = __shfl_up(incl, off);
    if (lane >= off) incl += v;
  }
  if (lane == 63) wtot[w] = incl;
  float sn[4];
#pragma unroll
  for (int k = 0; k < 4; ++k) sn[k] = src1t[n * 4 + k];
  __syncthreads();
  int base = 0;
  for (int w2 = 0; w2 < w; ++w2) base += wtot[w2];
  int cnt = wtot[0] + wtot[1] + wtot[2] + wtot[3];
  int pos = base + incl - pc;
  while (M) {
    int c = __builtin_ctz(M);
    lst[pos++] = (u16b)(t * 16 + c);
    M &= M - 1;
  }
  __syncthreads();
  // ---- leaky-relu logits: thread j -> (li=j>>2, k=j&3)
  for (int j = t; j < cnt * 4; j += 256) {
    int li = j >> 2, k = j & 3;
    int m = lst[li];
    float e = sn[k] + dst1t[m * 4 + k];
    ew[k][li] = e > 0.f ? e : 0.2f * e;
  }
  __syncthreads();
  // ---- per-wave softmax over head w, normalize in place
  {
    float mx = -1e30f, sm = 0.f;
    for (int li = lane; li < cnt; li += 64) {
      float e = ew[w][li];
      if (e > mx) { sm = sm * __expf(mx - e) + 1.f; mx = e; }
      else sm += __expf(e - mx);
    }
#pragma unroll
    for (int off = 32; off >= 1; off >>= 1) {
      float mo = __shfl_xor(mx, off);
      float so = __shfl_xor(sm, off);
      float Mx = fmaxf(mx, mo);
      sm = sm * __expf(mx - Mx) + so * __expf(mo - Mx);
      mx = Mx;
    }
    float R = 1.f / sm;
    for (int li = lane; li < cnt; li += 64)
      ew[w][li] = __expf(ew[w][li] - mx) * R;
  }
  __syncthreads();
  // ---- weighted gather: thread t owns cols 2t, 2t+1 (head == w)
  float a0 = 0.f, a1 = 0.f;
  const float* ewk = ew[w];
#pragma unroll 4
  for (int li = 0; li < cnt; ++li) {
    int m = lst[li];
    float wv = ewk[li];
    unsigned uu = *(const unsigned*)(Wh1bf + (size_t)m * 512 + 2 * t);
    a0 = fmaf(wv, bflo(uu), a0);
    a1 = fmaf(wv, bfhi(uu), a1);
  }
  a0 = a0 > 0.f ? a0 : __expf(a0) - 1.f;       // ELU
  a1 = a1 > 0.f ? a1 : __expf(a1) - 1.f;
  h1row[2 * t] = a0;
  h1row[2 * t + 1] = a1;
  __syncthreads();
  // ---- fused layer-2 projection (per-wave partial over 128 inputs)
  {
    int o = lane & 15, ig = lane >> 4;
    float accw = 0.f;
    for (int i = w * 128 + ig; i < (w + 1) * 128; i += 4)
      accw = fmaf(h1row[i], W2[i * 16 + o], accw);
    accw += __shfl_xor(accw, 16);
    accw += __shfl_xor(accw, 32);
    if (lane < 16) redw[w][o] = accw;
  }
  __syncthreads();
  if (t < 16) {
    float v = redw[0][t] + redw[1][t] + redw[2][t] + redw[3][t];
    Wh2[n * 16 + t] = v;
    float ps = v * as2[t];
    float pd = v * ad2[t];
#pragma unroll
    for (int off = 8; off >= 1; off >>= 1) {
      ps += __shfl_xor(ps, off, 16);
      pd += __shfl_xor(pd, off, 16);
    }
    if (t == 0) { src2[n] = ps; dst2[n] = pd; }
  }
}

// ---- D3: decode mask + layer-2 attention + log_softmax. One wave per row.
__global__ __launch_bounds__(256) void k_attn2(const u16b* __restrict__ mask,
    const float* __restrict__ Wh2, const float* __restrict__ src2,
    const float* __restrict__ dst2, float* __restrict__ out) {
  int w = threadIdx.x >> 6, lane = threadIdx.x & 63;
  int n = blockIdx.x * 4 + w;
  __shared__ u16b lst4[4][512];
  u16b* lst = lst4[w];
  // decode: lane l owns cols [64l, 64l+64)
  unsigned long long B = *(const unsigned long long*)((const char*)mask + (size_t)n * 512 + lane * 8);
  int pc = __popcll(B);
  int incl = pc;
#pragma unroll
  for (int off = 1; off <= 32; off <<= 1) {
    int v = __shfl_up(incl, off);
    if (lane >= off) incl += v;
  }
  int cnt = __shfl(incl, 63);
  int pos = incl - pc;
  while (B) {
    int c = __builtin_ctzll(B);
    lst[pos++] = (u16b)(lane * 64 + c);
    B &= B - 1;
  }
  // no cross-wave sharing: lst4[w] written and read by wave w only (wave-coherent LDS)
  float snv = src2[n];
  float mx = -1e30f, sm = 0.f;
  for (int li = lane; li < cnt; li += 64) {
    int m = lst[li];
    float e = snv + dst2[m]; e = e > 0.f ? e : 0.2f * e;
    if (e > mx) { sm = sm * __expf(mx - e) + 1.f; mx = e; }
    else sm += __expf(e - mx);
  }
#pragma unroll
  for (int off = 32; off >= 1; off >>= 1) {
    float mo = __shfl_xor(mx, off);
    float so = __shfl_xor(sm, off);
    float M = fmaxf(mx, mo);
    sm = sm * __expf(mx - M) + so * __expf(mo - M);
    mx = M;
  }
  float R = 1.f / sm;
  int o = lane & 15, g = lane >> 4;
  float acc = 0.f;
  for (int li = g; li < cnt; li += 4) {
    int m = lst[li];
    float e = snv + dst2[m]; e = e > 0.f ? e : 0.2f * e;
    float wgt = __expf(e - mx) * R;
    acc = fmaf(wgt, Wh2[m * 16 + o], acc);
  }
  acc += __shfl_xor(acc, 16);
  acc += __shfl_xor(acc, 32);
  float vm = acc;
#pragma unroll
  for (int off = 8; off >= 1; off >>= 1) vm = fmaxf(vm, __shfl_xor(vm, off, 16));
  float ex = __expf(acc - vm);
#pragma unroll
  for (int off = 8; off >= 1; off >>= 1) ex += __shfl_xor(ex, off, 16);
  if (lane < 16) out[(size_t)n * 16 + lane] = acc - vm - __logf(ex);
}

extern "C" void kernel_launch(void* const* d_in, const int* in_sizes, int n_in,
                              void* d_out, int out_size, void* d_ws, size_t ws_size,
                              hipStream_t stream) {
  const float* X   = (const float*)d_in[0];
  const float* adj = (const float*)d_in[1];
  const float* W1  = (const float*)d_in[2];
  const float* as1 = (const float*)d_in[3];
  const float* ad1 = (const float*)d_in[4];
  const float* W2  = (const float*)d_in[5];
  const float* as2 = (const float*)d_in[6];
  const float* ad2 = (const float*)d_in[7];
  float* out = (float*)d_out;

  // workspace (8 MB)
  char* ws = (char*)d_ws;
  float* src1t = (float*)ws;                         // 64 KB  [n][k]
  float* dst1t = (float*)(ws + (64 << 10));          // 64 KB  [n][k]
  float* src2  = (float*)(ws + (128 << 10));         // 16 KB
  float* dst2  = (float*)(ws + (144 << 10));         // 16 KB
  float* Wh2   = (float*)(ws + (160 << 10));         // 256 KB
  u16b*  mask  = (u16b*)(ws + (512 << 10));          // 2 MB   [n][256] u16 bitmask
  u16b*  Wh1bf = (u16b*)(ws + (4ull << 20));         // 4 MB   [n][k*128+h]

  k_fused1<<<dim3(2304), dim3(512), 0, stream>>>(adj, X, W1, as1, ad1,
                                                 mask, Wh1bf, src1t, dst1t);
  k_attn1<<<dim3(GN), dim3(256), 0, stream>>>(mask, Wh1bf, src1t, dst1t,
                                              W2, as2, ad2, Wh2, src2, dst2);
  k_attn2<<<dim3(1024), dim3(256), 0, stream>>>(mask, Wh2, src2, dst2, out);
}